// Round 1
// baseline (3503.699 us; speedup 1.0000x reference)
//
#include <hip/hip_runtime.h>

typedef __bf16 bhalf;
typedef __bf16 bh8_t __attribute__((ext_vector_type(8)));
typedef float f4_t __attribute__((ext_vector_type(4)));

#define MFMA16(A, B, C) __builtin_amdgcn_mfma_f32_16x16x32_bf16((A), (B), (C), 0, 0, 0)

// Problem sizes (fixed by setup_inputs)
// B=32768, D_IN=128, H=1024, N_FLUX=512, N_MET=256, N_IN=128

// Workspace layout (bf16 elements):
//  W1t  [1024][128]  = W1^T            (B operand for hidden = input @ W1)
//  W2t  [512][1024]  = W2^T            (B operand for V0 = hidden @ W2)
//  SPin [384][512]   = rows 0-255: S, rows 256-383: Pin   (B for [T|U] = V @ [S^T|Pin^T])
//  St   [512][256]   = S^T * 2^-7      (B for dV2 = T @ S * 2/256, scale folded, exact)
//  Pt   [512][128]   = Pin^T * 2^-6    (B for dV3 = relu @ Pin * 2/128, scale folded, exact)
#define OFF_W1T  0
#define OFF_W2T  (OFF_W1T + 1024 * 128)
#define OFF_SPIN (OFF_W2T + 512 * 1024)
#define OFF_ST   (OFF_SPIN + 384 * 512)
#define OFF_PT   (OFF_ST + 512 * 256)
// total = 1,048,576 bf16 elements = 2 MiB

__global__ __launch_bounds__(256) void amn_prep(
    const float* __restrict__ W1, const float* __restrict__ W2,
    const float* __restrict__ S, const float* __restrict__ Pin,
    bhalf* __restrict__ ws) {
  unsigned i = blockIdx.x * 256u + threadIdx.x;
  if (i < 131072u) {                   // W1t[n][k] = W1[k][n]
    unsigned n = i >> 7, k = i & 127u;
    ws[OFF_W1T + i] = (bhalf)W1[k * 1024u + n];
  } else if (i < 655360u) {            // W2t[n][k] = W2[k][n]
    unsigned j = i - 131072u;
    unsigned n = j >> 10, k = j & 1023u;
    ws[OFF_W2T + j] = (bhalf)W2[k * 512u + n];
  } else if (i < 851968u) {            // SPin: [S ; Pin] row-major
    unsigned j = i - 655360u;
    unsigned r = j >> 9, k = j & 511u;
    float v = (r < 256u) ? S[r * 512u + k] : Pin[(r - 256u) * 512u + k];
    ws[OFF_SPIN + j] = (bhalf)v;
  } else if (i < 983040u) {            // St[n][k] = S[k][n] * 2/256
    unsigned j = i - 851968u;
    unsigned n = j >> 8, k = j & 255u;
    ws[OFF_ST + j] = (bhalf)(S[k * 512u + n] * 0.0078125f);
  } else if (i < 1048576u) {           // Pt[n][k] = Pin[k][n] * 2/128
    unsigned j = i - 983040u;
    unsigned n = j >> 7, k = j & 127u;
    ws[OFF_PT + j] = (bhalf)(Pin[k * 512u + n] * 0.015625f);
  }
}

__device__ inline bh8_t cvt8(f4_t f0, f4_t f1) {
  bh8_t r;
  r[0] = (bhalf)f0[0]; r[1] = (bhalf)f0[1]; r[2] = (bhalf)f0[2]; r[3] = (bhalf)f0[3];
  r[4] = (bhalf)f1[0]; r[5] = (bhalf)f1[1]; r[6] = (bhalf)f1[2]; r[7] = (bhalf)f1[3];
  return r;
}

// One block = 32 rows of V, 512 threads = 8 waves.
// Wave w ownership:
//   phase (ii) [T|U] = V @ [S^T | Pin^T]: n-tiles {3w,3w+1,3w+2} of 24 (tiles 0-15 = T, 16-23 = U)
//   phase (iii) dV and V/diff state:      n-tiles {4w..4w+3} of 32 (cols 64w..64w+63)
// Each wave covers BOTH m-tiles -> every B fragment is loaded exactly once per block (no L2 dup).
__global__ __launch_bounds__(512) void amn_main(
    const float* __restrict__ input, const float* __restrict__ Vin,
    const float* __restrict__ b1, const float* __restrict__ b2,
    const int* __restrict__ niter_p,
    const bhalf* __restrict__ ws, float* __restrict__ out) {

  const unsigned tid = threadIdx.x;
  const unsigned w  = tid >> 6;    // wave 0..7
  const unsigned l  = tid & 63u;
  const unsigned lq = l >> 4;      // 0..3 (k-group / row-group)
  const unsigned lr = l & 15u;     // 0..15 (m for A, n-col for B, col for C/D)
  const unsigned row0 = blockIdx.x * 32u;

  const bhalf* W1t  = ws + OFF_W1T;
  const bhalf* W2t  = ws + OFF_W2T;
  const bhalf* SPin = ws + OFF_SPIN;
  const bhalf* St   = ws + OFF_ST;
  const bhalf* Pt   = ws + OFF_PT;

  // LDS: hid [32][1032] (MLP phase) aliases {V [32][520] | T [32][264] | R [32][136]} (loop phase)
  __shared__ __align__(16) bhalf smem[33024];  // 66,048 B
  bhalf* hid_lds = smem;
  bhalf* V_lds = smem;
  bhalf* T_lds = smem + 32 * 520;
  bhalf* R_lds = smem + 32 * 520 + 32 * 264;

  // ---- Vin preload into registers (only U-region tiles, t>=16; wave-uniform cond) ----
  float vinr[3][2][4] = {};
#pragma unroll
  for (int tt = 0; tt < 3; ++tt) {
    int t = 3 * (int)w + tt;
    if (t >= 16) {
      int u = t - 16;
#pragma unroll
      for (int mt = 0; mt < 2; ++mt)
#pragma unroll
        for (int r = 0; r < 4; ++r)
          vinr[tt][mt][r] = Vin[(row0 + 16u * mt + 4u * lq + r) * 128u + 16u * u + lr];
    }
  }

  // ================= MLP phase 1: hidden = relu(input @ W1 + b1) =================
  {
    f4_t hacc[2][8];
#pragma unroll
    for (int mt = 0; mt < 2; ++mt)
#pragma unroll
      for (int t = 0; t < 8; ++t) hacc[mt][t] = (f4_t)0.f;

#pragma unroll
    for (int k = 0; k < 4; ++k) {   // K = 128
      bh8_t a[2];
#pragma unroll
      for (int mt = 0; mt < 2; ++mt) {
        const float* ap = input + (row0 + 16u * mt + lr) * 128u + k * 32 + lq * 8u;
        f4_t f0 = *(const f4_t*)ap;
        f4_t f1 = *(const f4_t*)(ap + 4);
        a[mt] = cvt8(f0, f1);
      }
#pragma unroll
      for (int t = 0; t < 8; ++t) {
        bh8_t b = *(const bh8_t*)(W1t + (16u * (8u * w + t) + lr) * 128u + k * 32 + lq * 8u);
        hacc[0][t] = MFMA16(a[0], b, hacc[0][t]);
        hacc[1][t] = MFMA16(a[1], b, hacc[1][t]);
      }
    }
#pragma unroll
    for (int t = 0; t < 8; ++t) {
      unsigned col = 16u * (8u * w + t) + lr;
      float bias = b1[col];
#pragma unroll
      for (int mt = 0; mt < 2; ++mt)
#pragma unroll
        for (int r = 0; r < 4; ++r) {
          float v = fmaxf(hacc[mt][t][r] + bias, 0.f);
          hid_lds[(16u * mt + 4u * lq + r) * 1032u + col] = (bhalf)v;
        }
    }
  }
  __syncthreads();

  // ================= MLP phase 2: V0 = hidden @ W2 + b2 =================
  f4_t Vreg[2][4];
#pragma unroll
  for (int mt = 0; mt < 2; ++mt)
#pragma unroll
    for (int n = 0; n < 4; ++n) Vreg[mt][n] = (f4_t)0.f;

#pragma unroll
  for (int k = 0; k < 32; ++k) {  // K = 1024
    bh8_t a0 = *(const bh8_t*)(hid_lds + lr * 1032u + k * 32 + lq * 8u);
    bh8_t a1 = *(const bh8_t*)(hid_lds + (16u + lr) * 1032u + k * 32 + lq * 8u);
#pragma unroll
    for (int n = 0; n < 4; ++n) {
      bh8_t b = *(const bh8_t*)(W2t + (16u * (4u * w + n) + lr) * 1024u + k * 32 + lq * 8u);
      Vreg[0][n] = MFMA16(a0, b, Vreg[0][n]);
      Vreg[1][n] = MFMA16(a1, b, Vreg[1][n]);
    }
  }
#pragma unroll
  for (int n = 0; n < 4; ++n) {
    float bias = b2[16u * (4u * w + n) + lr];
#pragma unroll
    for (int mt = 0; mt < 2; ++mt)
#pragma unroll
      for (int r = 0; r < 4; ++r) Vreg[mt][n][r] += bias;
  }
  __syncthreads();  // all hid_lds reads done before V_lds writes (aliased)

  // ================= 30 momentum iterations =================
  f4_t Dreg[2][4];
#pragma unroll
  for (int mt = 0; mt < 2; ++mt)
#pragma unroll
    for (int n = 0; n < 4; ++n) Dreg[mt][n] = (f4_t)0.f;

  const int niter = niter_p[0];
  for (int it = 0; it < niter; ++it) {
    // ---- (i) stage V (bf16) to LDS ----
#pragma unroll
    for (int mt = 0; mt < 2; ++mt)
#pragma unroll
      for (int n = 0; n < 4; ++n) {
        unsigned col = 64u * w + 16u * n + lr;
#pragma unroll
        for (int r = 0; r < 4; ++r)
          V_lds[(16u * mt + 4u * lq + r) * 520u + col] = (bhalf)Vreg[mt][n][r];
      }
    __syncthreads();

    // ---- (ii) [T|U] = V @ [S^T | Pin^T], K = 512 ----
    f4_t acc[2][3];
#pragma unroll
    for (int mt = 0; mt < 2; ++mt)
#pragma unroll
      for (int tt = 0; tt < 3; ++tt) acc[mt][tt] = (f4_t)0.f;

#pragma unroll
    for (int k = 0; k < 16; ++k) {
      bh8_t a0 = *(const bh8_t*)(V_lds + lr * 520u + k * 32 + lq * 8u);
      bh8_t a1 = *(const bh8_t*)(V_lds + (16u + lr) * 520u + k * 32 + lq * 8u);
#pragma unroll
      for (int tt = 0; tt < 3; ++tt) {
        bh8_t b = *(const bh8_t*)(SPin + (16u * (3u * w + tt) + lr) * 512u + k * 32 + lq * 8u);
        acc[0][tt] = MFMA16(a0, b, acc[0][tt]);
        acc[1][tt] = MFMA16(a1, b, acc[1][tt]);
      }
    }
    // store T (bf16) / relu(U - Vin) (bf16)
#pragma unroll
    for (int tt = 0; tt < 3; ++tt) {
      int t = 3 * (int)w + tt;
      if (t < 16) {
#pragma unroll
        for (int mt = 0; mt < 2; ++mt)
#pragma unroll
          for (int r = 0; r < 4; ++r)
            T_lds[(16u * mt + 4u * lq + r) * 264u + 16u * t + lr] = (bhalf)acc[mt][tt][r];
      } else {
        int u = t - 16;
#pragma unroll
        for (int mt = 0; mt < 2; ++mt)
#pragma unroll
          for (int r = 0; r < 4; ++r)
            R_lds[(16u * mt + 4u * lq + r) * 136u + 16u * u + lr] =
                (bhalf)fmaxf(acc[mt][tt][r] - vinr[tt][mt][r], 0.f);
      }
    }
    __syncthreads();

    // ---- (iii) dV = T @ (S*2/256) + relu @ (Pin*2/128) ----
    f4_t dacc[2][4];
#pragma unroll
    for (int mt = 0; mt < 2; ++mt)
#pragma unroll
      for (int n = 0; n < 4; ++n) dacc[mt][n] = (f4_t)0.f;

#pragma unroll
    for (int k = 0; k < 8; ++k) {   // K = 256 (T @ St)
      bh8_t a0 = *(const bh8_t*)(T_lds + lr * 264u + k * 32 + lq * 8u);
      bh8_t a1 = *(const bh8_t*)(T_lds + (16u + lr) * 264u + k * 32 + lq * 8u);
#pragma unroll
      for (int n = 0; n < 4; ++n) {
        bh8_t b = *(const bh8_t*)(St + (16u * (4u * w + n) + lr) * 256u + k * 32 + lq * 8u);
        dacc[0][n] = MFMA16(a0, b, dacc[0][n]);
        dacc[1][n] = MFMA16(a1, b, dacc[1][n]);
      }
    }
#pragma unroll
    for (int k = 0; k < 4; ++k) {   // K = 128 (relu @ Pt)
      bh8_t a0 = *(const bh8_t*)(R_lds + lr * 136u + k * 32 + lq * 8u);
      bh8_t a1 = *(const bh8_t*)(R_lds + (16u + lr) * 136u + k * 32 + lq * 8u);
#pragma unroll
      for (int n = 0; n < 4; ++n) {
        bh8_t b = *(const bh8_t*)(Pt + (16u * (4u * w + n) + lr) * 128u + k * 32 + lq * 8u);
        dacc[0][n] = MFMA16(a0, b, dacc[0][n]);
        dacc[1][n] = MFMA16(a1, b, dacc[1][n]);
      }
    }

    // ---- update: dV += min(V,0)*2/512; diff = 0.9 diff - 0.01 dV; V += diff ----
#pragma unroll
    for (int mt = 0; mt < 2; ++mt)
#pragma unroll
      for (int n = 0; n < 4; ++n)
#pragma unroll
        for (int r = 0; r < 4; ++r) {
          float dv = dacc[mt][n][r] + fminf(Vreg[mt][n][r], 0.f) * 0.00390625f;
          float d = 0.9f * Dreg[mt][n][r] - 0.01f * dv;
          Dreg[mt][n][r] = d;
          Vreg[mt][n][r] += d;
        }
  }

  // ---- write final V (fp32) ----
#pragma unroll
  for (int mt = 0; mt < 2; ++mt)
#pragma unroll
    for (int n = 0; n < 4; ++n) {
      unsigned col = 64u * w + 16u * n + lr;
#pragma unroll
      for (int r = 0; r < 4; ++r)
        out[(row0 + 16u * mt + 4u * lq + r) * 512u + col] = Vreg[mt][n][r];
    }
}

extern "C" void kernel_launch(void* const* d_in, const int* in_sizes, int n_in,
                              void* d_out, int out_size, void* d_ws, size_t ws_size,
                              hipStream_t stream) {
  const float* input = (const float*)d_in[0];
  // d_in[1] = Vref (unused by reference)
  const float* Vin = (const float*)d_in[2];
  const float* W1  = (const float*)d_in[3];
  const float* b1  = (const float*)d_in[4];
  const float* W2  = (const float*)d_in[5];
  const float* b2  = (const float*)d_in[6];
  const float* S   = (const float*)d_in[7];
  const float* Pin = (const float*)d_in[8];
  const int* nit   = (const int*)d_in[9];
  bhalf* ws  = (bhalf*)d_ws;
  float* out = (float*)d_out;

  amn_prep<<<4096, 256, 0, stream>>>(W1, W2, S, Pin, ws);
  amn_main<<<1024, 512, 0, stream>>>(input, Vin, b1, b2, nit, ws, out);
}

// Round 2
// 3424.565 us; speedup vs baseline: 1.0231x; 1.0231x over previous
//
#include <hip/hip_runtime.h>

typedef __bf16 bhalf;
typedef __bf16 bh8_t __attribute__((ext_vector_type(8)));
typedef float f4_t __attribute__((ext_vector_type(4)));

#define MFMA16(A, B, C) __builtin_amdgcn_mfma_f32_16x16x32_bf16((A), (B), (C), 0, 0, 0)

// Problem sizes: B=32768, D_IN=128, H=1024, N_FLUX=512, N_MET=256, N_IN=128
// M = 64 rows per block, 512 blocks, 512 threads (8 waves), 4 m-tiles/wave.

// Workspace layout (bf16 elements):
//  W1t  [1024][128]  = W1^T
//  W2t  [512][1024]  = W2^T
//  SPin [384][512]   = rows 0-255: S, rows 256-383: Pin
//  St   [512][256]   = S^T * 2/256
//  Pt   [512][128]   = Pin^T * 2/128
#define OFF_W1T  0
#define OFF_W2T  (OFF_W1T + 1024 * 128)
#define OFF_SPIN (OFF_W2T + 512 * 1024)
#define OFF_ST   (OFF_SPIN + 384 * 512)
#define OFF_PT   (OFF_ST + 512 * 256)

__global__ __launch_bounds__(256) void amn_prep(
    const float* __restrict__ W1, const float* __restrict__ W2,
    const float* __restrict__ S, const float* __restrict__ Pin,
    bhalf* __restrict__ ws) {
  unsigned i = blockIdx.x * 256u + threadIdx.x;
  if (i < 131072u) {                   // W1t[n][k] = W1[k][n]
    unsigned n = i >> 7, k = i & 127u;
    ws[OFF_W1T + i] = (bhalf)W1[k * 1024u + n];
  } else if (i < 655360u) {            // W2t[n][k] = W2[k][n]
    unsigned j = i - 131072u;
    unsigned n = j >> 10, k = j & 1023u;
    ws[OFF_W2T + j] = (bhalf)W2[k * 512u + n];
  } else if (i < 851968u) {            // SPin: [S ; Pin] row-major
    unsigned j = i - 655360u;
    unsigned r = j >> 9, k = j & 511u;
    float v = (r < 256u) ? S[r * 512u + k] : Pin[(r - 256u) * 512u + k];
    ws[OFF_SPIN + j] = (bhalf)v;
  } else if (i < 983040u) {            // St[n][k] = S[k][n] * 2/256
    unsigned j = i - 851968u;
    unsigned n = j >> 8, k = j & 255u;
    ws[OFF_ST + j] = (bhalf)(S[k * 512u + n] * 0.0078125f);
  } else if (i < 1048576u) {           // Pt[n][k] = Pin[k][n] * 2/128
    unsigned j = i - 983040u;
    unsigned n = j >> 7, k = j & 127u;
    ws[OFF_PT + j] = (bhalf)(Pin[k * 512u + n] * 0.015625f);
  }
}

__device__ inline bh8_t cvt8(f4_t f0, f4_t f1) {
  bh8_t r;
  r[0] = (bhalf)f0[0]; r[1] = (bhalf)f0[1]; r[2] = (bhalf)f0[2]; r[3] = (bhalf)f0[3];
  r[4] = (bhalf)f1[0]; r[5] = (bhalf)f1[1]; r[6] = (bhalf)f1[2]; r[7] = (bhalf)f1[3];
  return r;
}

// LDS map (bf16 element offsets; total 75264 elem = 150,528 B):
//   V_lds  [64][520]  @ 0       (66,560 B)
//   T_lds  [64][264]  @ 33280   (33,792 B)
//   R_lds  [64][136]  @ 50176   (17,408 B)
//   Vin    [64][128]  @ 58880   (f32, 32,768 B)  -- loaded AFTER MLP (aliases hid tail)
//   hid    [64][1032] @ 0       (132,096 B, MLP phase only, aliases all of the above)
#define SM_TOTAL 75264
#define SMV   0
#define SMT   33280
#define SMR   50176
#define SMVIN 58880

__global__ __launch_bounds__(512) void amn_main(
    const float* __restrict__ input, const float* __restrict__ Vin,
    const float* __restrict__ b1, const float* __restrict__ b2,
    const int* __restrict__ niter_p,
    const bhalf* __restrict__ ws, float* __restrict__ out) {

  const unsigned tid = threadIdx.x;
  const unsigned w  = tid >> 6;    // wave 0..7
  const unsigned l  = tid & 63u;
  const unsigned lq = l >> 4;      // 0..3
  const unsigned lr = l & 15u;     // 0..15
  const unsigned row0 = blockIdx.x * 64u;

  const bhalf* W1t  = ws + OFF_W1T;
  const bhalf* W2t  = ws + OFF_W2T;
  const bhalf* SPin = ws + OFF_SPIN;
  const bhalf* St   = ws + OFF_ST;
  const bhalf* Pt   = ws + OFF_PT;

  __shared__ __align__(16) bhalf smem[SM_TOTAL];
  bhalf* V_lds  = smem + SMV;
  bhalf* T_lds  = smem + SMT;
  bhalf* R_lds  = smem + SMR;
  float* Vin_lds = (float*)(smem + SMVIN);
  bhalf* hid_lds = smem;

  // ================= MLP phase 1: hidden = relu(input @ W1 + b1) =================
  {
    f4_t hacc[4][8];
#pragma unroll
    for (int mt = 0; mt < 4; ++mt)
#pragma unroll
      for (int t = 0; t < 8; ++t) hacc[mt][t] = (f4_t)0.f;

#pragma unroll
    for (int k = 0; k < 4; ++k) {   // K = 128
      bh8_t a[4];
#pragma unroll
      for (int mt = 0; mt < 4; ++mt) {
        const float* ap = input + (row0 + 16u * mt + lr) * 128u + k * 32 + lq * 8u;
        f4_t f0 = *(const f4_t*)ap;
        f4_t f1 = *(const f4_t*)(ap + 4);
        a[mt] = cvt8(f0, f1);
      }
#pragma unroll
      for (int t = 0; t < 8; ++t) {
        bh8_t b = *(const bh8_t*)(W1t + (16u * (8u * w + t) + lr) * 128u + k * 32 + lq * 8u);
#pragma unroll
        for (int mt = 0; mt < 4; ++mt) hacc[mt][t] = MFMA16(a[mt], b, hacc[mt][t]);
      }
    }
#pragma unroll
    for (int t = 0; t < 8; ++t) {
      unsigned col = 16u * (8u * w + t) + lr;
      float bias = b1[col];
#pragma unroll
      for (int mt = 0; mt < 4; ++mt)
#pragma unroll
        for (int r = 0; r < 4; ++r) {
          float v = fmaxf(hacc[mt][t][r] + bias, 0.f);
          hid_lds[(16u * mt + 4u * lq + r) * 1032u + col] = (bhalf)v;
        }
    }
  }
  __syncthreads();

  // ================= MLP phase 2: V0 = hidden @ W2 + b2 =================
  f4_t Vreg[4][4];
#pragma unroll
  for (int mt = 0; mt < 4; ++mt)
#pragma unroll
    for (int n = 0; n < 4; ++n) Vreg[mt][n] = (f4_t)0.f;

#pragma unroll
  for (int k = 0; k < 32; ++k) {  // K = 1024
    bh8_t a[4];
#pragma unroll
    for (int mt = 0; mt < 4; ++mt)
      a[mt] = *(const bh8_t*)(hid_lds + (16u * mt + lr) * 1032u + k * 32 + lq * 8u);
#pragma unroll
    for (int n = 0; n < 4; ++n) {
      bh8_t b = *(const bh8_t*)(W2t + (16u * (4u * w + n) + lr) * 1024u + k * 32 + lq * 8u);
#pragma unroll
      for (int mt = 0; mt < 4; ++mt) Vreg[mt][n] = MFMA16(a[mt], b, Vreg[mt][n]);
    }
  }
#pragma unroll
  for (int n = 0; n < 4; ++n) {
    float bias = b2[16u * (4u * w + n) + lr];
#pragma unroll
    for (int mt = 0; mt < 4; ++mt)
#pragma unroll
      for (int r = 0; r < 4; ++r) Vreg[mt][n][r] += bias;
  }
  __syncthreads();  // hid_lds dead from here; V/T/R/Vin regions become live

  // ---- load Vin (fp32) into LDS once: 64 rows x 128 cols ----
  {
    const float* vsrc = Vin + row0 * 128u;
#pragma unroll
    for (int j = 0; j < 4; ++j) {
      unsigned idx = tid * 4u + j * 2048u;         // 512 threads x 4 floats x 4 passes
      *(f4_t*)(Vin_lds + idx * 0 + 0) ;            // no-op keep simple below
    }
    // simple flat copy: 8192 floats, 512 threads, f4 per thread per pass
#pragma unroll
    for (int p = 0; p < 4; ++p) {
      unsigned idx = (p * 512u + tid) * 4u;        // 0..8188 step 4
      *(f4_t*)(Vin_lds + idx) = *(const f4_t*)(vsrc + idx);
    }
  }

  // ================= 30 momentum iterations =================
  f4_t Dreg[4][4];
#pragma unroll
  for (int mt = 0; mt < 4; ++mt)
#pragma unroll
    for (int n = 0; n < 4; ++n) Dreg[mt][n] = (f4_t)0.f;

  const int niter = niter_p[0];
  for (int it = 0; it < niter; ++it) {
    // ---- (i) stage V (bf16) to LDS ----
#pragma unroll
    for (int mt = 0; mt < 4; ++mt)
#pragma unroll
      for (int n = 0; n < 4; ++n) {
        unsigned col = 64u * w + 16u * n + lr;
#pragma unroll
        for (int r = 0; r < 4; ++r)
          V_lds[(16u * mt + 4u * lq + r) * 520u + col] = (bhalf)Vreg[mt][n][r];
      }
    __syncthreads();

    // ---- (ii) [T|U] = V @ [S^T | Pin^T], K = 512 ----
    f4_t acc[4][3];
#pragma unroll
    for (int mt = 0; mt < 4; ++mt)
#pragma unroll
      for (int tt = 0; tt < 3; ++tt) acc[mt][tt] = (f4_t)0.f;

#pragma unroll
    for (int k = 0; k < 16; ++k) {
      bh8_t a[4];
#pragma unroll
      for (int mt = 0; mt < 4; ++mt)
        a[mt] = *(const bh8_t*)(V_lds + (16u * mt + lr) * 520u + k * 32 + lq * 8u);
#pragma unroll
      for (int tt = 0; tt < 3; ++tt) {
        bh8_t b = *(const bh8_t*)(SPin + (16u * (3u * w + tt) + lr) * 512u + k * 32 + lq * 8u);
#pragma unroll
        for (int mt = 0; mt < 4; ++mt) acc[mt][tt] = MFMA16(a[mt], b, acc[mt][tt]);
      }
    }
    // store T (bf16) / relu(U - Vin) (bf16)
#pragma unroll
    for (int tt = 0; tt < 3; ++tt) {
      int t = 3 * (int)w + tt;
      if (t < 16) {
#pragma unroll
        for (int mt = 0; mt < 4; ++mt)
#pragma unroll
          for (int r = 0; r < 4; ++r)
            T_lds[(16u * mt + 4u * lq + r) * 264u + 16u * t + lr] = (bhalf)acc[mt][tt][r];
      } else {
        int u = t - 16;
#pragma unroll
        for (int mt = 0; mt < 4; ++mt)
#pragma unroll
          for (int r = 0; r < 4; ++r) {
            float vin = Vin_lds[(16u * mt + 4u * lq + r) * 128u + 16u * u + lr];
            R_lds[(16u * mt + 4u * lq + r) * 136u + 16u * u + lr] =
                (bhalf)fmaxf(acc[mt][tt][r] - vin, 0.f);
          }
      }
    }
    __syncthreads();

    // ---- (iii) dV = T @ (S*2/256) + relu @ (Pin*2/128) ----
    f4_t dacc[4][4];
#pragma unroll
    for (int mt = 0; mt < 4; ++mt)
#pragma unroll
      for (int n = 0; n < 4; ++n) dacc[mt][n] = (f4_t)0.f;

#pragma unroll
    for (int k = 0; k < 8; ++k) {   // K = 256 (T @ St)
      bh8_t a[4];
#pragma unroll
      for (int mt = 0; mt < 4; ++mt)
        a[mt] = *(const bh8_t*)(T_lds + (16u * mt + lr) * 264u + k * 32 + lq * 8u);
#pragma unroll
      for (int n = 0; n < 4; ++n) {
        bh8_t b = *(const bh8_t*)(St + (16u * (4u * w + n) + lr) * 256u + k * 32 + lq * 8u);
#pragma unroll
        for (int mt = 0; mt < 4; ++mt) dacc[mt][n] = MFMA16(a[mt], b, dacc[mt][n]);
      }
    }
#pragma unroll
    for (int k = 0; k < 4; ++k) {   // K = 128 (relu @ Pt)
      bh8_t a[4];
#pragma unroll
      for (int mt = 0; mt < 4; ++mt)
        a[mt] = *(const bh8_t*)(R_lds + (16u * mt + lr) * 136u + k * 32 + lq * 8u);
#pragma unroll
      for (int n = 0; n < 4; ++n) {
        bh8_t b = *(const bh8_t*)(Pt + (16u * (4u * w + n) + lr) * 128u + k * 32 + lq * 8u);
#pragma unroll
        for (int mt = 0; mt < 4; ++mt) dacc[mt][n] = MFMA16(a[mt], b, dacc[mt][n]);
      }
    }

    // ---- update: dV += min(V,0)*2/512; diff = 0.9 diff - 0.01 dV; V += diff ----
#pragma unroll
    for (int mt = 0; mt < 4; ++mt)
#pragma unroll
      for (int n = 0; n < 4; ++n)
#pragma unroll
        for (int r = 0; r < 4; ++r) {
          float dv = dacc[mt][n][r] + fminf(Vreg[mt][n][r], 0.f) * 0.00390625f;
          float d = 0.9f * Dreg[mt][n][r] - 0.01f * dv;
          Dreg[mt][n][r] = d;
          Vreg[mt][n][r] += d;
        }
  }

  // ---- write final V (fp32) ----
#pragma unroll
  for (int mt = 0; mt < 4; ++mt)
#pragma unroll
    for (int n = 0; n < 4; ++n) {
      unsigned col = 64u * w + 16u * n + lr;
#pragma unroll
      for (int r = 0; r < 4; ++r)
        out[(row0 + 16u * mt + 4u * lq + r) * 512u + col] = Vreg[mt][n][r];
    }
}

extern "C" void kernel_launch(void* const* d_in, const int* in_sizes, int n_in,
                              void* d_out, int out_size, void* d_ws, size_t ws_size,
                              hipStream_t stream) {
  const float* input = (const float*)d_in[0];
  // d_in[1] = Vref (unused by reference)
  const float* Vin = (const float*)d_in[2];
  const float* W1  = (const float*)d_in[3];
  const float* b1  = (const float*)d_in[4];
  const float* W2  = (const float*)d_in[5];
  const float* b2  = (const float*)d_in[6];
  const float* S   = (const float*)d_in[7];
  const float* Pin = (const float*)d_in[8];
  const int* nit   = (const int*)d_in[9];
  bhalf* ws  = (bhalf*)d_ws;
  float* out = (float*)d_out;

  amn_prep<<<4096, 256, 0, stream>>>(W1, W2, S, Pin, ws);
  amn_main<<<512, 512, 0, stream>>>(input, Vin, b1, b2, nit, ws, out);
}

// Round 3
// 3148.129 us; speedup vs baseline: 1.1129x; 1.0878x over previous
//
#include <hip/hip_runtime.h>

typedef __bf16 bhalf;
typedef __bf16 bh8_t __attribute__((ext_vector_type(8)));
typedef float f4_t __attribute__((ext_vector_type(4)));

#define MFMA16(A, B, C) __builtin_amdgcn_mfma_f32_16x16x32_bf16((A), (B), (C), 0, 0, 0)

// Problem sizes: B=32768, D_IN=128, H=1024, N_FLUX=512, N_MET=256, N_IN=128
// M = 64 rows per block, 512 blocks, 512 threads (8 waves), 4 m-tiles/wave.
// __launch_bounds__(512,2): cap 256 regs/wave -> ~230-reg live set fits, NO SPILL
// (round 2's default targeted 128 VGPRs -> ~2 GB spill writes + 2 GB reads/dispatch,
//  scratch thrashed L2 and caused the 55% miss rate on the 768 KB B-operand set).

// Workspace layout (bf16 elements):
//  W1t  [1024][128]  = W1^T
//  W2t  [512][1024]  = W2^T
//  SPin [384][512]   = rows 0-255: S, rows 256-383: Pin
//  St   [512][256]   = S^T * 2/256
//  Pt   [512][128]   = Pin^T * 2/128
#define OFF_W1T  0
#define OFF_W2T  (OFF_W1T + 1024 * 128)
#define OFF_SPIN (OFF_W2T + 512 * 1024)
#define OFF_ST   (OFF_SPIN + 384 * 512)
#define OFF_PT   (OFF_ST + 512 * 256)

__global__ __launch_bounds__(256) void amn_prep(
    const float* __restrict__ W1, const float* __restrict__ W2,
    const float* __restrict__ S, const float* __restrict__ Pin,
    bhalf* __restrict__ ws) {
  unsigned i = blockIdx.x * 256u + threadIdx.x;
  if (i < 131072u) {                   // W1t[n][k] = W1[k][n]
    unsigned n = i >> 7, k = i & 127u;
    ws[OFF_W1T + i] = (bhalf)W1[k * 1024u + n];
  } else if (i < 655360u) {            // W2t[n][k] = W2[k][n]
    unsigned j = i - 131072u;
    unsigned n = j >> 10, k = j & 1023u;
    ws[OFF_W2T + j] = (bhalf)W2[k * 512u + n];
  } else if (i < 851968u) {            // SPin: [S ; Pin] row-major
    unsigned j = i - 655360u;
    unsigned r = j >> 9, k = j & 511u;
    float v = (r < 256u) ? S[r * 512u + k] : Pin[(r - 256u) * 512u + k];
    ws[OFF_SPIN + j] = (bhalf)v;
  } else if (i < 983040u) {            // St[n][k] = S[k][n] * 2/256
    unsigned j = i - 851968u;
    unsigned n = j >> 8, k = j & 255u;
    ws[OFF_ST + j] = (bhalf)(S[k * 512u + n] * 0.0078125f);
  } else if (i < 1048576u) {           // Pt[n][k] = Pin[k][n] * 2/128
    unsigned j = i - 983040u;
    unsigned n = j >> 7, k = j & 127u;
    ws[OFF_PT + j] = (bhalf)(Pin[k * 512u + n] * 0.015625f);
  }
}

__device__ inline bh8_t cvt8(f4_t f0, f4_t f1) {
  bh8_t r;
  r[0] = (bhalf)f0[0]; r[1] = (bhalf)f0[1]; r[2] = (bhalf)f0[2]; r[3] = (bhalf)f0[3];
  r[4] = (bhalf)f1[0]; r[5] = (bhalf)f1[1]; r[6] = (bhalf)f1[2]; r[7] = (bhalf)f1[3];
  return r;
}

// LDS map (bf16 element offsets; total 75264 elem = 150,528 B):
//   V_lds  [64][520]  @ 0       (66,560 B)
//   T_lds  [64][264]  @ 33280   (33,792 B)
//   R_lds  [64][136]  @ 50176   (17,408 B)
//   Vin    [64][128]  @ 58880   (f32, 32,768 B)
//   hid    [64][1032] @ 0       (132,096 B, MLP phase only, aliases all of the above)
#define SM_TOTAL 75264
#define SMV   0
#define SMT   33280
#define SMR   50176
#define SMVIN 58880

__global__ __launch_bounds__(512, 2) void amn_main(
    const float* __restrict__ input, const float* __restrict__ Vin,
    const float* __restrict__ b1, const float* __restrict__ b2,
    const int* __restrict__ niter_p,
    const bhalf* __restrict__ ws, float* __restrict__ out) {

  const unsigned tid = threadIdx.x;
  const unsigned w  = tid >> 6;    // wave 0..7
  const unsigned l  = tid & 63u;
  const unsigned lq = l >> 4;      // 0..3
  const unsigned lr = l & 15u;     // 0..15
  const unsigned row0 = blockIdx.x * 64u;

  const bhalf* W1t  = ws + OFF_W1T;
  const bhalf* W2t  = ws + OFF_W2T;
  const bhalf* SPin = ws + OFF_SPIN;
  const bhalf* St   = ws + OFF_ST;
  const bhalf* Pt   = ws + OFF_PT;

  __shared__ __align__(16) bhalf smem[SM_TOTAL];
  bhalf* V_lds  = smem + SMV;
  bhalf* T_lds  = smem + SMT;
  bhalf* R_lds  = smem + SMR;
  float* Vin_lds = (float*)(smem + SMVIN);
  bhalf* hid_lds = smem;

  // ================= MLP phase 1: hidden = relu(input @ W1 + b1) =================
  {
    f4_t hacc[4][8];
#pragma unroll
    for (int mt = 0; mt < 4; ++mt)
#pragma unroll
      for (int t = 0; t < 8; ++t) hacc[mt][t] = (f4_t)0.f;

#pragma unroll
    for (int k = 0; k < 4; ++k) {   // K = 128
      bh8_t a[4];
#pragma unroll
      for (int mt = 0; mt < 4; ++mt) {
        const float* ap = input + (row0 + 16u * mt + lr) * 128u + k * 32 + lq * 8u;
        f4_t f0 = *(const f4_t*)ap;
        f4_t f1 = *(const f4_t*)(ap + 4);
        a[mt] = cvt8(f0, f1);
      }
#pragma unroll
      for (int t = 0; t < 8; ++t) {
        bh8_t b = *(const bh8_t*)(W1t + (16u * (8u * w + t) + lr) * 128u + k * 32 + lq * 8u);
#pragma unroll
        for (int mt = 0; mt < 4; ++mt) hacc[mt][t] = MFMA16(a[mt], b, hacc[mt][t]);
      }
    }
#pragma unroll
    for (int t = 0; t < 8; ++t) {
      unsigned col = 16u * (8u * w + t) + lr;
      float bias = b1[col];
#pragma unroll
      for (int mt = 0; mt < 4; ++mt)
#pragma unroll
        for (int r = 0; r < 4; ++r) {
          float v = fmaxf(hacc[mt][t][r] + bias, 0.f);
          hid_lds[(16u * mt + 4u * lq + r) * 1032u + col] = (bhalf)v;
        }
    }
  }
  __syncthreads();

  // ================= MLP phase 2: V0 = hidden @ W2 + b2 =================
  f4_t Vreg[4][4];
#pragma unroll
  for (int mt = 0; mt < 4; ++mt)
#pragma unroll
    for (int n = 0; n < 4; ++n) Vreg[mt][n] = (f4_t)0.f;

#pragma unroll
  for (int k = 0; k < 32; ++k) {  // K = 1024
    bh8_t a[4];
#pragma unroll
    for (int mt = 0; mt < 4; ++mt)
      a[mt] = *(const bh8_t*)(hid_lds + (16u * mt + lr) * 1032u + k * 32 + lq * 8u);
#pragma unroll
    for (int n = 0; n < 4; ++n) {
      bh8_t b = *(const bh8_t*)(W2t + (16u * (4u * w + n) + lr) * 1024u + k * 32 + lq * 8u);
#pragma unroll
      for (int mt = 0; mt < 4; ++mt) Vreg[mt][n] = MFMA16(a[mt], b, Vreg[mt][n]);
    }
  }
#pragma unroll
  for (int n = 0; n < 4; ++n) {
    float bias = b2[16u * (4u * w + n) + lr];
#pragma unroll
    for (int mt = 0; mt < 4; ++mt)
#pragma unroll
      for (int r = 0; r < 4; ++r) Vreg[mt][n][r] += bias;
  }
  __syncthreads();  // hid_lds dead from here; V/T/R/Vin regions become live

  // ---- load Vin (fp32) into LDS once: 64 rows x 128 cols ----
  {
    const float* vsrc = Vin + row0 * 128u;
#pragma unroll
    for (int p = 0; p < 4; ++p) {
      unsigned idx = (p * 512u + tid) * 4u;        // 8192 floats, f4 per thread per pass
      *(f4_t*)(Vin_lds + idx) = *(const f4_t*)(vsrc + idx);
    }
  }

  // ================= 30 momentum iterations =================
  f4_t Dreg[4][4];
#pragma unroll
  for (int mt = 0; mt < 4; ++mt)
#pragma unroll
    for (int n = 0; n < 4; ++n) Dreg[mt][n] = (f4_t)0.f;

  const int niter = niter_p[0];
  for (int it = 0; it < niter; ++it) {
    // ---- (i) stage V (bf16) to LDS ----
#pragma unroll
    for (int mt = 0; mt < 4; ++mt)
#pragma unroll
      for (int n = 0; n < 4; ++n) {
        unsigned col = 64u * w + 16u * n + lr;
#pragma unroll
        for (int r = 0; r < 4; ++r)
          V_lds[(16u * mt + 4u * lq + r) * 520u + col] = (bhalf)Vreg[mt][n][r];
      }
    __syncthreads();

    // ---- (ii) [T|U] = V @ [S^T | Pin^T], K = 512 ----
    f4_t acc[4][3];
#pragma unroll
    for (int mt = 0; mt < 4; ++mt)
#pragma unroll
      for (int tt = 0; tt < 3; ++tt) acc[mt][tt] = (f4_t)0.f;

#pragma unroll
    for (int k = 0; k < 16; ++k) {
      bh8_t a[4];
#pragma unroll
      for (int mt = 0; mt < 4; ++mt)
        a[mt] = *(const bh8_t*)(V_lds + (16u * mt + lr) * 520u + k * 32 + lq * 8u);
#pragma unroll
      for (int tt = 0; tt < 3; ++tt) {
        bh8_t b = *(const bh8_t*)(SPin + (16u * (3u * w + tt) + lr) * 512u + k * 32 + lq * 8u);
#pragma unroll
        for (int mt = 0; mt < 4; ++mt) acc[mt][tt] = MFMA16(a[mt], b, acc[mt][tt]);
      }
    }
    // store T (bf16) / relu(U - Vin) (bf16)
#pragma unroll
    for (int tt = 0; tt < 3; ++tt) {
      int t = 3 * (int)w + tt;
      if (t < 16) {
#pragma unroll
        for (int mt = 0; mt < 4; ++mt)
#pragma unroll
          for (int r = 0; r < 4; ++r)
            T_lds[(16u * mt + 4u * lq + r) * 264u + 16u * t + lr] = (bhalf)acc[mt][tt][r];
      } else {
        int u = t - 16;
#pragma unroll
        for (int mt = 0; mt < 4; ++mt)
#pragma unroll
          for (int r = 0; r < 4; ++r) {
            float vin = Vin_lds[(16u * mt + 4u * lq + r) * 128u + 16u * u + lr];
            R_lds[(16u * mt + 4u * lq + r) * 136u + 16u * u + lr] =
                (bhalf)fmaxf(acc[mt][tt][r] - vin, 0.f);
          }
      }
    }
    __syncthreads();

    // ---- (iii) dV = T @ (S*2/256) + relu @ (Pin*2/128) ----
    f4_t dacc[4][4];
#pragma unroll
    for (int mt = 0; mt < 4; ++mt)
#pragma unroll
      for (int n = 0; n < 4; ++n) dacc[mt][n] = (f4_t)0.f;

#pragma unroll
    for (int k = 0; k < 8; ++k) {   // K = 256 (T @ St)
      bh8_t a[4];
#pragma unroll
      for (int mt = 0; mt < 4; ++mt)
        a[mt] = *(const bh8_t*)(T_lds + (16u * mt + lr) * 264u + k * 32 + lq * 8u);
#pragma unroll
      for (int n = 0; n < 4; ++n) {
        bh8_t b = *(const bh8_t*)(St + (16u * (4u * w + n) + lr) * 256u + k * 32 + lq * 8u);
#pragma unroll
        for (int mt = 0; mt < 4; ++mt) dacc[mt][n] = MFMA16(a[mt], b, dacc[mt][n]);
      }
    }
#pragma unroll
    for (int k = 0; k < 4; ++k) {   // K = 128 (relu @ Pt)
      bh8_t a[4];
#pragma unroll
      for (int mt = 0; mt < 4; ++mt)
        a[mt] = *(const bh8_t*)(R_lds + (16u * mt + lr) * 136u + k * 32 + lq * 8u);
#pragma unroll
      for (int n = 0; n < 4; ++n) {
        bh8_t b = *(const bh8_t*)(Pt + (16u * (4u * w + n) + lr) * 128u + k * 32 + lq * 8u);
#pragma unroll
        for (int mt = 0; mt < 4; ++mt) dacc[mt][n] = MFMA16(a[mt], b, dacc[mt][n]);
      }
    }

    // ---- update: dV += min(V,0)*2/512; diff = 0.9 diff - 0.01 dV; V += diff ----
#pragma unroll
    for (int mt = 0; mt < 4; ++mt)
#pragma unroll
      for (int n = 0; n < 4; ++n)
#pragma unroll
        for (int r = 0; r < 4; ++r) {
          float dv = dacc[mt][n][r] + fminf(Vreg[mt][n][r], 0.f) * 0.00390625f;
          float d = 0.9f * Dreg[mt][n][r] - 0.01f * dv;
          Dreg[mt][n][r] = d;
          Vreg[mt][n][r] += d;
        }
  }

  // ---- write final V (fp32) ----
#pragma unroll
  for (int mt = 0; mt < 4; ++mt)
#pragma unroll
    for (int n = 0; n < 4; ++n) {
      unsigned col = 64u * w + 16u * n + lr;
#pragma unroll
      for (int r = 0; r < 4; ++r)
        out[(row0 + 16u * mt + 4u * lq + r) * 512u + col] = Vreg[mt][n][r];
    }
}

extern "C" void kernel_launch(void* const* d_in, const int* in_sizes, int n_in,
                              void* d_out, int out_size, void* d_ws, size_t ws_size,
                              hipStream_t stream) {
  const float* input = (const float*)d_in[0];
  // d_in[1] = Vref (unused by reference)
  const float* Vin = (const float*)d_in[2];
  const float* W1  = (const float*)d_in[3];
  const float* b1  = (const float*)d_in[4];
  const float* W2  = (const float*)d_in[5];
  const float* b2  = (const float*)d_in[6];
  const float* S   = (const float*)d_in[7];
  const float* Pin = (const float*)d_in[8];
  const int* nit   = (const int*)d_in[9];
  bhalf* ws  = (bhalf*)d_ws;
  float* out = (float*)d_out;

  amn_prep<<<4096, 256, 0, stream>>>(W1, W2, S, Pin, ws);
  amn_main<<<512, 512, 0, stream>>>(input, Vin, b1, b2, nit, ws, out);
}

// Round 4
// 2862.040 us; speedup vs baseline: 1.2242x; 1.1000x over previous
//
#include <hip/hip_runtime.h>

typedef __bf16 bhalf;
typedef __bf16 bh8_t __attribute__((ext_vector_type(8)));
typedef float f4_t __attribute__((ext_vector_type(4)));

#define MFMA16(A, B, C) __builtin_amdgcn_mfma_f32_16x16x32_bf16((A), (B), (C), 0, 0, 0)

// Problem sizes: B=32768, D_IN=128, H=1024, N_FLUX=512, N_MET=256, N_IN=128
// M = 64 rows per block, 512 blocks, 512 threads (8 waves), 4 m-tiles/wave.
//
// __launch_bounds__(512, 1): LDS (150 KB) already limits to 1 block/CU, so a
// 128-VGPR occupancy target is pure loss — rounds 2/3 spilled ~2 GB/dispatch
// to scratch and thrashed L2 (6.4 MB scratch/XCD vs 4 MB L2). Allow 256 VGPRs.
// Phase (iii) is restructured per-n-tile (dacc transient 64 -> 16 regs) so the
// peak live set (~190) sits comfortably under the 256 cap: zero spill.

// Workspace layout (bf16 elements):
//  W1t  [1024][128]  = W1^T
//  W2t  [512][1024]  = W2^T
//  SPin [384][512]   = rows 0-255: S, rows 256-383: Pin
//  St   [512][256]   = S^T * 2/256
//  Pt   [512][128]   = Pin^T * 2/128
#define OFF_W1T  0
#define OFF_W2T  (OFF_W1T + 1024 * 128)
#define OFF_SPIN (OFF_W2T + 512 * 1024)
#define OFF_ST   (OFF_SPIN + 384 * 512)
#define OFF_PT   (OFF_ST + 512 * 256)

__global__ __launch_bounds__(256) void amn_prep(
    const float* __restrict__ W1, const float* __restrict__ W2,
    const float* __restrict__ S, const float* __restrict__ Pin,
    bhalf* __restrict__ ws) {
  unsigned i = blockIdx.x * 256u + threadIdx.x;
  if (i < 131072u) {                   // W1t[n][k] = W1[k][n]
    unsigned n = i >> 7, k = i & 127u;
    ws[OFF_W1T + i] = (bhalf)W1[k * 1024u + n];
  } else if (i < 655360u) {            // W2t[n][k] = W2[k][n]
    unsigned j = i - 131072u;
    unsigned n = j >> 10, k = j & 1023u;
    ws[OFF_W2T + j] = (bhalf)W2[k * 512u + n];
  } else if (i < 851968u) {            // SPin: [S ; Pin] row-major
    unsigned j = i - 655360u;
    unsigned r = j >> 9, k = j & 511u;
    float v = (r < 256u) ? S[r * 512u + k] : Pin[(r - 256u) * 512u + k];
    ws[OFF_SPIN + j] = (bhalf)v;
  } else if (i < 983040u) {            // St[n][k] = S[k][n] * 2/256
    unsigned j = i - 851968u;
    unsigned n = j >> 8, k = j & 255u;
    ws[OFF_ST + j] = (bhalf)(S[k * 512u + n] * 0.0078125f);
  } else if (i < 1048576u) {           // Pt[n][k] = Pin[k][n] * 2/128
    unsigned j = i - 983040u;
    unsigned n = j >> 7, k = j & 127u;
    ws[OFF_PT + j] = (bhalf)(Pin[k * 512u + n] * 0.015625f);
  }
}

__device__ inline bh8_t cvt8(f4_t f0, f4_t f1) {
  bh8_t r;
  r[0] = (bhalf)f0[0]; r[1] = (bhalf)f0[1]; r[2] = (bhalf)f0[2]; r[3] = (bhalf)f0[3];
  r[4] = (bhalf)f1[0]; r[5] = (bhalf)f1[1]; r[6] = (bhalf)f1[2]; r[7] = (bhalf)f1[3];
  return r;
}

// LDS map (bf16 element offsets; total 75264 elem = 150,528 B):
//   V_lds  [64][520]  @ 0       (66,560 B)
//   T_lds  [64][264]  @ 33280   (33,792 B)
//   R_lds  [64][136]  @ 50176   (17,408 B)
//   Vin    [64][128]  @ 58880   (f32, 32,768 B)
//   hid    [64][1032] @ 0       (132,096 B, MLP phase only, aliases all of the above)
#define SM_TOTAL 75264
#define SMV   0
#define SMT   33280
#define SMR   50176
#define SMVIN 58880

__global__ __launch_bounds__(512, 1) void amn_main(
    const float* __restrict__ input, const float* __restrict__ Vin,
    const float* __restrict__ b1, const float* __restrict__ b2,
    const int* __restrict__ niter_p,
    const bhalf* __restrict__ ws, float* __restrict__ out) {

  const unsigned tid = threadIdx.x;
  const unsigned w  = tid >> 6;    // wave 0..7
  const unsigned l  = tid & 63u;
  const unsigned lq = l >> 4;      // 0..3
  const unsigned lr = l & 15u;     // 0..15
  const unsigned row0 = blockIdx.x * 64u;

  const bhalf* W1t  = ws + OFF_W1T;
  const bhalf* W2t  = ws + OFF_W2T;
  const bhalf* SPin = ws + OFF_SPIN;
  const bhalf* St   = ws + OFF_ST;
  const bhalf* Pt   = ws + OFF_PT;

  __shared__ __align__(16) bhalf smem[SM_TOTAL];
  bhalf* V_lds  = smem + SMV;
  bhalf* T_lds  = smem + SMT;
  bhalf* R_lds  = smem + SMR;
  float* Vin_lds = (float*)(smem + SMVIN);
  bhalf* hid_lds = smem;

  // ================= MLP phase 1: hidden = relu(input @ W1 + b1) =================
  {
    f4_t hacc[4][8];
#pragma unroll
    for (int mt = 0; mt < 4; ++mt)
#pragma unroll
      for (int t = 0; t < 8; ++t) hacc[mt][t] = (f4_t)0.f;

#pragma unroll
    for (int k = 0; k < 4; ++k) {   // K = 128
      bh8_t a[4];
#pragma unroll
      for (int mt = 0; mt < 4; ++mt) {
        const float* ap = input + (row0 + 16u * mt + lr) * 128u + k * 32 + lq * 8u;
        f4_t f0 = *(const f4_t*)ap;
        f4_t f1 = *(const f4_t*)(ap + 4);
        a[mt] = cvt8(f0, f1);
      }
#pragma unroll
      for (int t = 0; t < 8; ++t) {
        bh8_t b = *(const bh8_t*)(W1t + (16u * (8u * w + t) + lr) * 128u + k * 32 + lq * 8u);
#pragma unroll
        for (int mt = 0; mt < 4; ++mt) hacc[mt][t] = MFMA16(a[mt], b, hacc[mt][t]);
      }
    }
#pragma unroll
    for (int t = 0; t < 8; ++t) {
      unsigned col = 16u * (8u * w + t) + lr;
      float bias = b1[col];
#pragma unroll
      for (int mt = 0; mt < 4; ++mt)
#pragma unroll
        for (int r = 0; r < 4; ++r) {
          float v = fmaxf(hacc[mt][t][r] + bias, 0.f);
          hid_lds[(16u * mt + 4u * lq + r) * 1032u + col] = (bhalf)v;
        }
    }
  }
  __syncthreads();

  // ================= MLP phase 2: V0 = hidden @ W2 + b2 =================
  f4_t Vreg[4][4];
#pragma unroll
  for (int mt = 0; mt < 4; ++mt)
#pragma unroll
    for (int n = 0; n < 4; ++n) Vreg[mt][n] = (f4_t)0.f;

#pragma unroll
  for (int k = 0; k < 32; ++k) {  // K = 1024
    bh8_t a[4];
#pragma unroll
    for (int mt = 0; mt < 4; ++mt)
      a[mt] = *(const bh8_t*)(hid_lds + (16u * mt + lr) * 1032u + k * 32 + lq * 8u);
#pragma unroll
    for (int n = 0; n < 4; ++n) {
      bh8_t b = *(const bh8_t*)(W2t + (16u * (4u * w + n) + lr) * 1024u + k * 32 + lq * 8u);
#pragma unroll
      for (int mt = 0; mt < 4; ++mt) Vreg[mt][n] = MFMA16(a[mt], b, Vreg[mt][n]);
    }
  }
#pragma unroll
  for (int n = 0; n < 4; ++n) {
    float bias = b2[16u * (4u * w + n) + lr];
#pragma unroll
    for (int mt = 0; mt < 4; ++mt)
#pragma unroll
      for (int r = 0; r < 4; ++r) Vreg[mt][n][r] += bias;
  }
  __syncthreads();  // hid_lds dead from here; V/T/R/Vin regions become live

  // ---- load Vin (fp32) into LDS once: 64 rows x 128 cols ----
  {
    const float* vsrc = Vin + row0 * 128u;
#pragma unroll
    for (int p = 0; p < 4; ++p) {
      unsigned idx = (p * 512u + tid) * 4u;        // 8192 floats, f4 per thread per pass
      *(f4_t*)(Vin_lds + idx) = *(const f4_t*)(vsrc + idx);
    }
  }

  // ================= 30 momentum iterations =================
  f4_t Dreg[4][4];
#pragma unroll
  for (int mt = 0; mt < 4; ++mt)
#pragma unroll
    for (int n = 0; n < 4; ++n) Dreg[mt][n] = (f4_t)0.f;

  const int niter = niter_p[0];
  for (int it = 0; it < niter; ++it) {
    // ---- (i) stage V (bf16) to LDS ----
#pragma unroll
    for (int mt = 0; mt < 4; ++mt)
#pragma unroll
      for (int n = 0; n < 4; ++n) {
        unsigned col = 64u * w + 16u * n + lr;
#pragma unroll
        for (int r = 0; r < 4; ++r)
          V_lds[(16u * mt + 4u * lq + r) * 520u + col] = (bhalf)Vreg[mt][n][r];
      }
    __syncthreads();

    // ---- (ii) [T|U] = V @ [S^T | Pin^T], K = 512 ----
    f4_t acc[4][3];
#pragma unroll
    for (int mt = 0; mt < 4; ++mt)
#pragma unroll
      for (int tt = 0; tt < 3; ++tt) acc[mt][tt] = (f4_t)0.f;

#pragma unroll
    for (int k = 0; k < 16; ++k) {
      bh8_t a[4];
#pragma unroll
      for (int mt = 0; mt < 4; ++mt)
        a[mt] = *(const bh8_t*)(V_lds + (16u * mt + lr) * 520u + k * 32 + lq * 8u);
#pragma unroll
      for (int tt = 0; tt < 3; ++tt) {
        bh8_t b = *(const bh8_t*)(SPin + (16u * (3u * w + tt) + lr) * 512u + k * 32 + lq * 8u);
#pragma unroll
        for (int mt = 0; mt < 4; ++mt) acc[mt][tt] = MFMA16(a[mt], b, acc[mt][tt]);
      }
    }
    // store T (bf16) / relu(U - Vin) (bf16)
#pragma unroll
    for (int tt = 0; tt < 3; ++tt) {
      int t = 3 * (int)w + tt;
      if (t < 16) {
#pragma unroll
        for (int mt = 0; mt < 4; ++mt)
#pragma unroll
          for (int r = 0; r < 4; ++r)
            T_lds[(16u * mt + 4u * lq + r) * 264u + 16u * t + lr] = (bhalf)acc[mt][tt][r];
      } else {
        int u = t - 16;
#pragma unroll
        for (int mt = 0; mt < 4; ++mt)
#pragma unroll
          for (int r = 0; r < 4; ++r) {
            float vin = Vin_lds[(16u * mt + 4u * lq + r) * 128u + 16u * u + lr];
            R_lds[(16u * mt + 4u * lq + r) * 136u + 16u * u + lr] =
                (bhalf)fmaxf(acc[mt][tt][r] - vin, 0.f);
          }
      }
    }
    __syncthreads();

    // ---- (iii) per n-tile: dacc = T @ St + R @ Pt, then update V/diff ----
    // (per-n transient: 16 regs instead of 64 -> peak live ~190 < 256, no spill)
#pragma unroll
    for (int n = 0; n < 4; ++n) {
      f4_t dacc[4];
#pragma unroll
      for (int mt = 0; mt < 4; ++mt) dacc[mt] = (f4_t)0.f;

#pragma unroll
      for (int k = 0; k < 8; ++k) {   // K = 256 (T @ St)
        bh8_t b = *(const bh8_t*)(St + (16u * (4u * w + n) + lr) * 256u + k * 32 + lq * 8u);
#pragma unroll
        for (int mt = 0; mt < 4; ++mt) {
          bh8_t a = *(const bh8_t*)(T_lds + (16u * mt + lr) * 264u + k * 32 + lq * 8u);
          dacc[mt] = MFMA16(a, b, dacc[mt]);
        }
      }
#pragma unroll
      for (int k = 0; k < 4; ++k) {   // K = 128 (R @ Pt)
        bh8_t b = *(const bh8_t*)(Pt + (16u * (4u * w + n) + lr) * 128u + k * 32 + lq * 8u);
#pragma unroll
        for (int mt = 0; mt < 4; ++mt) {
          bh8_t a = *(const bh8_t*)(R_lds + (16u * mt + lr) * 136u + k * 32 + lq * 8u);
          dacc[mt] = MFMA16(a, b, dacc[mt]);
        }
      }

      // update: dV += min(V,0)*2/512; diff = 0.9 diff - 0.01 dV; V += diff
#pragma unroll
      for (int mt = 0; mt < 4; ++mt)
#pragma unroll
        for (int r = 0; r < 4; ++r) {
          float dv = dacc[mt][r] + fminf(Vreg[mt][n][r], 0.f) * 0.00390625f;
          float d = 0.9f * Dreg[mt][n][r] - 0.01f * dv;
          Dreg[mt][n][r] = d;
          Vreg[mt][n][r] += d;
        }
    }
  }

  // ---- write final V (fp32) ----
#pragma unroll
  for (int mt = 0; mt < 4; ++mt)
#pragma unroll
    for (int n = 0; n < 4; ++n) {
      unsigned col = 64u * w + 16u * n + lr;
#pragma unroll
      for (int r = 0; r < 4; ++r)
        out[(row0 + 16u * mt + 4u * lq + r) * 512u + col] = Vreg[mt][n][r];
    }
}

extern "C" void kernel_launch(void* const* d_in, const int* in_sizes, int n_in,
                              void* d_out, int out_size, void* d_ws, size_t ws_size,
                              hipStream_t stream) {
  const float* input = (const float*)d_in[0];
  // d_in[1] = Vref (unused by reference)
  const float* Vin = (const float*)d_in[2];
  const float* W1  = (const float*)d_in[3];
  const float* b1  = (const float*)d_in[4];
  const float* W2  = (const float*)d_in[5];
  const float* b2  = (const float*)d_in[6];
  const float* S   = (const float*)d_in[7];
  const float* Pin = (const float*)d_in[8];
  const int* nit   = (const int*)d_in[9];
  bhalf* ws  = (bhalf*)d_ws;
  float* out = (float*)d_out;

  amn_prep<<<4096, 256, 0, stream>>>(W1, W2, S, Pin, ws);
  amn_main<<<512, 512, 0, stream>>>(input, Vin, b1, b2, nit, ws, out);
}